// Round 8
// baseline (241.820 us; speedup 1.0000x reference)
//
#include <hip/hip_runtime.h>
#include <math.h>

constexpr int N  = 50000;
constexpr int E  = 800000;
constexpr int F1 = 128;
constexpr int F2 = 16;
constexpr int BSHIFT  = 8;                         // 256-node buckets
constexpr int NBUCKET = (N + 255) >> BSHIFT;       // 196
constexpr int CHUNK   = 8192;                      // edges per block in bin kernels

typedef unsigned short ushort_t;
typedef __bf16 bf16x8 __attribute__((ext_vector_type(8)));
typedef float  f32x4  __attribute__((ext_vector_type(4)));

static __device__ __forceinline__ float blo(unsigned u) { return __uint_as_float(u << 16); }
static __device__ __forceinline__ float bhi(unsigned u) { return __uint_as_float(u & 0xffff0000u); }
static __device__ __forceinline__ ushort_t to_bf(float f) { __bf16 h = (__bf16)f; return *(ushort_t*)&h; }

// ---------- CSR build, two-level (256-node buckets) + fused weight prep ----------
__global__ __launch_bounds__(256) void k_binCount(const int* __restrict__ col,
                                                  int* __restrict__ bucket_count,
                                                  const float* __restrict__ W1,
                                                  const float* __restrict__ W2,
                                                  ushort_t* __restrict__ W1t,
                                                  ushort_t* __restrict__ W2t) {
    __shared__ int hist[NBUCKET];
    int t = threadIdx.x;
    if (t < NBUCKET) hist[t] = 0;
    __syncthreads();
    int base = blockIdx.x * CHUNK;
#pragma unroll
    for (int i = 0; i < CHUNK / 256; ++i) {
        int e = base + i * 256 + t;
        if (e < E) atomicAdd(&hist[col[e] >> BSHIFT], 1);
    }
    __syncthreads();
    if (t < NBUCKET && hist[t]) atomicAdd(&bucket_count[t], hist[t]);

    int gi = blockIdx.x * 256 + t;
    if (gi < F1 * F1) {
        int k = gi >> 7, n = gi & 127;
        W1t[n * F1 + k] = to_bf(W1[gi]);
    }
    if (gi < F1 * F2) {
        int k = gi >> 4, n = gi & 15;
        W2t[n * F1 + k] = to_bf(W2[gi]);
    }
}

__global__ __launch_bounds__(256) void k_binScan(const int* __restrict__ bucket_count,
                                                 int* __restrict__ bucket_start,
                                                 int* __restrict__ bucket_cursor) {
    __shared__ int wtot[4];
    int t = threadIdx.x, lane = t & 63, wid = t >> 6;
    int v = (t < NBUCKET) ? bucket_count[t] : 0;
    int incl = v;
#pragma unroll
    for (int d = 1; d < 64; d <<= 1) {
        int u = __shfl_up(incl, d, 64);
        if (lane >= d) incl += u;
    }
    if (lane == 63) wtot[wid] = incl;
    __syncthreads();
    int wb = 0;
    for (int w = 0; w < wid; ++w) wb += wtot[w];
    int excl = wb + incl - v;
    if (t < NBUCKET) {
        bucket_start[t]  = excl;
        bucket_cursor[t] = excl;
    }
    if (t == NBUCKET - 1) bucket_start[NBUCKET] = excl + v;  // == E
}

__global__ __launch_bounds__(256) void k_binScatter(const int* __restrict__ row,
                                                    const int* __restrict__ col,
                                                    int* __restrict__ bucket_cursor,
                                                    unsigned* __restrict__ P) {
    __shared__ int hist[NBUCKET];
    __shared__ int cur[NBUCKET];
    int t = threadIdx.x;
    if (t < NBUCKET) hist[t] = 0;
    __syncthreads();
    int base = blockIdx.x * CHUNK;
#pragma unroll
    for (int i = 0; i < CHUNK / 256; ++i) {
        int e = base + i * 256 + t;
        if (e < E) atomicAdd(&hist[col[e] >> BSHIFT], 1);
    }
    __syncthreads();
    if (t < NBUCKET) cur[t] = atomicAdd(&bucket_cursor[t], hist[t]);
    __syncthreads();
#pragma unroll
    for (int i = 0; i < CHUNK / 256; ++i) {
        int e = base + i * 256 + t;
        if (e < E) {
            int c = col[e];
            int pos = atomicAdd(&cur[c >> BSHIFT], 1);
            P[pos] = ((unsigned)row[e] << BSHIFT) | (unsigned)(c & 255);
        }
    }
}

__global__ __launch_bounds__(256) void k_binFinal(const unsigned* __restrict__ P,
                                                  const int* __restrict__ bucket_start,
                                                  ushort_t* __restrict__ csr16,
                                                  int* __restrict__ seg_start,
                                                  int* __restrict__ counts,
                                                  float* __restrict__ dinv) {
    __shared__ int cnt[256];
    __shared__ int cur[256];
    __shared__ int wtot[4];
    int t = threadIdx.x, lane = t & 63, wid = t >> 6;
    int b = blockIdx.x;
    int lo = b << BSHIFT;
    int n_nodes = min(256, N - lo);
    cnt[t] = 0;
    __syncthreads();
    int s = bucket_start[b], e = bucket_start[b + 1];
    for (int k = s + t; k < e; k += 256)
        atomicAdd(&cnt[P[k] & 255], 1);
    __syncthreads();
    int v = cnt[t];
    int incl = v;
#pragma unroll
    for (int d = 1; d < 64; d <<= 1) {
        int u = __shfl_up(incl, d, 64);
        if (lane >= d) incl += u;
    }
    if (lane == 63) wtot[wid] = incl;
    __syncthreads();
    int wb = 0;
    for (int w = 0; w < wid; ++w) wb += wtot[w];
    int o = s + wb + incl - v;
    cur[t] = o;
    if (t < n_nodes) {
        seg_start[lo + t] = o;
        counts[lo + t] = v;
        dinv[lo + t] = rsqrtf((float)v + 1.f);
    }
    __syncthreads();
    for (int k = s + t; k < e; k += 256) {
        unsigned u = P[k];
        int pos = atomicAdd(&cur[u & 255], 1);
        csr16[pos] = (ushort_t)(u >> BSHIFT);
    }
}

// ---------- GEMM1 (MFMA bf16): h1s = bf16(dinv[r] * (x @ W1)[r]) ----------
__global__ __launch_bounds__(256) void k_gemm1_mfma(const float* __restrict__ x,
                                                    const ushort_t* __restrict__ W1t,
                                                    const float* __restrict__ dinv,
                                                    ushort_t* __restrict__ h1s) {
    __shared__ ushort_t Wl[F1 * 136];
    int t = threadIdx.x;
    for (int i = t; i < F1 * 16; i += 256) {
        int n = i >> 4, c = (i & 15) * 8;
        *(int4*)&Wl[n * 136 + c] = *(const int4*)&W1t[n * F1 + c];
    }
    __syncthreads();

    int lane = t & 63, wv = t >> 6;
    int quad = lane >> 4, l15 = lane & 15;
    int arow = blockIdx.x * 64 + wv * 16 + l15;
    int rclamp = min(arow, N - 1);
    f32x4 acc[8] = {};

#pragma unroll
    for (int kk = 0; kk < 4; ++kk) {
        int k0 = kk * 32 + quad * 8;
        const float* xp = x + (size_t)rclamp * F1 + k0;
        float4 u0 = *(const float4*)xp;
        float4 u1 = *(const float4*)(xp + 4);
        bf16x8 a;
        a[0] = (__bf16)u0.x; a[1] = (__bf16)u0.y; a[2] = (__bf16)u0.z; a[3] = (__bf16)u0.w;
        a[4] = (__bf16)u1.x; a[5] = (__bf16)u1.y; a[6] = (__bf16)u1.z; a[7] = (__bf16)u1.w;
#pragma unroll
        for (int ct = 0; ct < 8; ++ct) {
            bf16x8 b = *(const bf16x8*)&Wl[(ct * 16 + l15) * 136 + k0];
            acc[ct] = __builtin_amdgcn_mfma_f32_16x16x32_bf16(a, b, acc[ct], 0, 0, 0);
        }
    }

    int orow0 = blockIdx.x * 64 + wv * 16 + quad * 4;
#pragma unroll
    for (int r = 0; r < 4; ++r) {
        int orow = orow0 + r;
        if (orow < N) {
            float d = dinv[orow];
#pragma unroll
            for (int ct = 0; ct < 8; ++ct)
                h1s[(size_t)orow * F1 + ct * 16 + l15] = to_bf(acc[ct][r] * d);
        }
    }
}

// ---------- Gather 1, feature-quarter pass q: 16 lanes/node, bf16x2/lane ----------
// per pass the h1s slice is 3.2 MB -> per-XCD-L2 resident
__global__ __launch_bounds__(256) void k_gather1_q(const ushort_t* __restrict__ h1s,
                                                   const int* __restrict__ seg_start,
                                                   const int* __restrict__ counts,
                                                   const ushort_t* __restrict__ csr16,
                                                   const float* __restrict__ dinv,
                                                   const float* __restrict__ b1,
                                                   ushort_t* __restrict__ h1rb,
                                                   int q) {
    int idx = blockIdx.x * 256 + threadIdx.x;
    int c = idx >> 4, sub = idx & 15;
    if (c >= N) return;
    const unsigned* base = (const unsigned*)h1s + q * 16 + sub;  // row stride 64 dwords
    int s = seg_start[c], e = s + counts[c];
    float ax = 0.f, ay = 0.f;
    int k = s;
    for (; k + 4 <= e; k += 4) {
        int r0 = csr16[k], r1 = csr16[k + 1], r2 = csr16[k + 2], r3 = csr16[k + 3];
        unsigned u0 = base[(size_t)r0 * 64];
        unsigned u1 = base[(size_t)r1 * 64];
        unsigned u2 = base[(size_t)r2 * 64];
        unsigned u3 = base[(size_t)r3 * 64];
        ax += (blo(u0) + blo(u1)) + (blo(u2) + blo(u3));
        ay += (bhi(u0) + bhi(u1)) + (bhi(u2) + bhi(u3));
    }
    for (; k < e; ++k) {
        unsigned u = base[(size_t)csr16[k] * 64];
        ax += blo(u);
        ay += bhi(u);
    }
    unsigned us = base[(size_t)c * 64];
    ax += blo(us);
    ay += bhi(us);
    float dc = dinv[c];
    float2 bb = ((const float2*)b1)[q * 16 + sub];
    float o0 = fmaxf(fmaf(dc, ax, bb.x), 0.f);
    float o1 = fmaxf(fmaf(dc, ay, bb.y), 0.f);
    unsigned pw = (unsigned)to_bf(o0) | ((unsigned)to_bf(o1) << 16);
    ((unsigned*)h1rb)[(size_t)c * 64 + q * 16 + sub] = pw;
}

// ---------- GEMM2 (MFMA bf16): h2s = bf16(dinv[r] * (h1r @ W2)[r]) ----------
__global__ __launch_bounds__(256) void k_gemm2_mfma(const ushort_t* __restrict__ h1rb,
                                                    const ushort_t* __restrict__ W2t,
                                                    const float* __restrict__ dinv,
                                                    ushort_t* __restrict__ h2s) {
    int t = threadIdx.x, lane = t & 63, wv = t >> 6;
    int quad = lane >> 4, l15 = lane & 15;
    int arow = blockIdx.x * 64 + wv * 16 + l15;
    int rclamp = min(arow, N - 1);
    f32x4 acc = {};
#pragma unroll
    for (int kk = 0; kk < 4; ++kk) {
        int k0 = kk * 32 + quad * 8;
        bf16x8 a = *(const bf16x8*)(h1rb + (size_t)rclamp * F1 + k0);
        bf16x8 b = *(const bf16x8*)(W2t + l15 * F1 + k0);
        acc = __builtin_amdgcn_mfma_f32_16x16x32_bf16(a, b, acc, 0, 0, 0);
    }
    int orow0 = blockIdx.x * 64 + wv * 16 + quad * 4;
#pragma unroll
    for (int r = 0; r < 4; ++r) {
        int orow = orow0 + r;
        if (orow < N)
            h2s[(size_t)orow * F2 + l15] = to_bf(acc[r] * dinv[orow]);
    }
}

// ---------- Gather 2 + log_softmax: 8 lanes/node ----------
__global__ __launch_bounds__(256) void k_gather2(const ushort_t* __restrict__ h2s,
                                                 const int* __restrict__ seg_start,
                                                 const int* __restrict__ counts,
                                                 const ushort_t* __restrict__ csr16,
                                                 const float* __restrict__ dinv,
                                                 const float* __restrict__ b2,
                                                 float* __restrict__ out) {
    int idx = blockIdx.x * 256 + threadIdx.x;
    int node = idx >> 3, sub = idx & 7;
    if (node >= N) return;
    int s = seg_start[node], e = s + counts[node];
    float ax = 0.f, ay = 0.f;
    int k = s;
    for (; k + 4 <= e; k += 4) {
        int r0 = csr16[k], r1 = csr16[k + 1], r2 = csr16[k + 2], r3 = csr16[k + 3];
        unsigned u0 = ((const unsigned*)(h2s + (size_t)r0 * F2))[sub];
        unsigned u1 = ((const unsigned*)(h2s + (size_t)r1 * F2))[sub];
        unsigned u2 = ((const unsigned*)(h2s + (size_t)r2 * F2))[sub];
        unsigned u3 = ((const unsigned*)(h2s + (size_t)r3 * F2))[sub];
        ax += (blo(u0) + blo(u1)) + (blo(u2) + blo(u3));
        ay += (bhi(u0) + bhi(u1)) + (bhi(u2) + bhi(u3));
    }
    for (; k < e; ++k) {
        unsigned u = ((const unsigned*)(h2s + (size_t)csr16[k] * F2))[sub];
        ax += blo(u);
        ay += bhi(u);
    }
    unsigned us = ((const unsigned*)(h2s + (size_t)node * F2))[sub];
    ax += blo(us);
    ay += bhi(us);
    float dc = dinv[node];
    float2 bb = ((const float2*)b2)[sub];
    float v0 = fmaf(dc, ax, bb.x);
    float v1 = fmaf(dc, ay, bb.y);
    float mx = fmaxf(v0, v1);
#pragma unroll
    for (int m = 1; m < 8; m <<= 1) mx = fmaxf(mx, __shfl_xor(mx, m));
    float sm = expf(v0 - mx) + expf(v1 - mx);
#pragma unroll
    for (int m = 1; m < 8; m <<= 1) sm += __shfl_xor(sm, m);
    float lse = mx + logf(sm);
    float2 o;
    o.x = v0 - lse;
    o.y = v1 - lse;
    ((float2*)(out + (size_t)node * F2))[sub] = o;
}

extern "C" void kernel_launch(void* const* d_in, const int* in_sizes, int n_in,
                              void* d_out, int out_size, void* d_ws, size_t ws_size,
                              hipStream_t stream) {
    const float* x  = (const float*)d_in[0];
    const int*   ei = (const int*)d_in[1];
    const float* W1 = (const float*)d_in[2];
    const float* b1 = (const float*)d_in[3];
    const float* W2 = (const float*)d_in[4];
    const float* b2 = (const float*)d_in[5];
    const int* row = ei;
    const int* col = ei + E;

    char* ws = (char*)d_ws;
    int*      bucket_count  = (int*)ws;  ws += 256 * 4;
    int*      bucket_start  = (int*)ws;  ws += 256 * 4;
    int*      bucket_cursor = (int*)ws;  ws += 256 * 4;
    unsigned* P             = (unsigned*)ws; ws += (size_t)E * 4;
    ushort_t* csr16         = (ushort_t*)ws; ws += (size_t)(E + 8) * 2;
    int*      seg_start     = (int*)ws;  ws += (size_t)N * 4;
    int*      counts        = (int*)ws;  ws += (size_t)N * 4;
    float*    dinv          = (float*)ws; ws += (size_t)N * 4;
    ushort_t* W1t           = (ushort_t*)ws; ws += (size_t)F1 * F1 * 2;
    ushort_t* W2t           = (ushort_t*)ws; ws += (size_t)F2 * F1 * 2;
    ushort_t* h1s           = (ushort_t*)ws; ws += (size_t)N * F1 * 2;
    ushort_t* h1rb          = (ushort_t*)ws; ws += (size_t)N * F1 * 2;
    ushort_t* h2s           = (ushort_t*)ws; ws += (size_t)N * F2 * 2;

    hipMemsetAsync(bucket_count, 0, 256 * 4, stream);

    int nbin_blocks = (E + CHUNK - 1) / CHUNK;  // 98
    k_binCount<<<nbin_blocks, 256, 0, stream>>>(col, bucket_count, W1, W2, W1t, W2t);
    k_binScan<<<1, 256, 0, stream>>>(bucket_count, bucket_start, bucket_cursor);
    k_binScatter<<<nbin_blocks, 256, 0, stream>>>(row, col, bucket_cursor, P);
    k_binFinal<<<NBUCKET, 256, 0, stream>>>(P, bucket_start, csr16, seg_start, counts, dinv);

    k_gemm1_mfma<<<(N + 63) / 64, 256, 0, stream>>>(x, W1t, dinv, h1s);
    int g1_blocks = ((size_t)N * 16 + 255) / 256;  // 3125
    for (int q = 0; q < 4; ++q)
        k_gather1_q<<<g1_blocks, 256, 0, stream>>>(h1s, seg_start, counts, csr16, dinv, b1,
                                                   h1rb, q);

    k_gemm2_mfma<<<(N + 63) / 64, 256, 0, stream>>>(h1rb, W2t, dinv, h2s);
    k_gather2<<<((size_t)N * 8 + 255) / 256, 256, 0, stream>>>(h2s, seg_start, counts, csr16,
                                                               dinv, b2, (float*)d_out);
}

// Round 9
// 184.474 us; speedup vs baseline: 1.3109x; 1.3109x over previous
//
#include <hip/hip_runtime.h>
#include <math.h>

constexpr int N  = 50000;
constexpr int E  = 800000;
constexpr int F1 = 128;
constexpr int F2 = 16;
constexpr int BSHIFT  = 8;                    // 256-node buckets
constexpr int NBUCKET = (N + 255) >> BSHIFT;  // 196
constexpr int CHUNK   = 8192;                 // edges per block in scatterP
constexpr int CAP     = 6144;                 // per-bucket capacity (mean 4096, sigma 64)

typedef unsigned short ushort_t;
typedef __bf16 bf16x8 __attribute__((ext_vector_type(8)));
typedef float  f32x4  __attribute__((ext_vector_type(4)));

static __device__ __forceinline__ float blo(unsigned u) { return __uint_as_float(u << 16); }
static __device__ __forceinline__ float bhi(unsigned u) { return __uint_as_float(u & 0xffff0000u); }
static __device__ __forceinline__ ushort_t to_bf(float f) { __bf16 h = (__bf16)f; return *(ushort_t*)&h; }

// ---------- fused bucket scatter (replaces count+scan+scatter) + weight prep ----------
// P[b*CAP + i] = row<<8 | (col & 255), per-bucket cursors in global
__global__ __launch_bounds__(256) void k_scatterP(const int* __restrict__ row,
                                                  const int* __restrict__ col,
                                                  int* __restrict__ cursor,
                                                  unsigned* __restrict__ P,
                                                  const float* __restrict__ W1,
                                                  const float* __restrict__ W2,
                                                  ushort_t* __restrict__ W1t,
                                                  ushort_t* __restrict__ W2t) {
    __shared__ int hist[NBUCKET];
    __shared__ int cur[NBUCKET];
    int t = threadIdx.x;
    if (t < NBUCKET) hist[t] = 0;
    __syncthreads();
    int base = blockIdx.x * CHUNK;
#pragma unroll
    for (int i = 0; i < CHUNK / 256; ++i) {
        int e = base + i * 256 + t;
        if (e < E) atomicAdd(&hist[col[e] >> BSHIFT], 1);
    }
    __syncthreads();
    if (t < NBUCKET) cur[t] = t * CAP + atomicAdd(&cursor[t], hist[t]);
    __syncthreads();
#pragma unroll
    for (int i = 0; i < CHUNK / 256; ++i) {
        int e = base + i * 256 + t;
        if (e < E) {
            int c = col[e];
            int pos = atomicAdd(&cur[c >> BSHIFT], 1);
            P[pos] = ((unsigned)row[e] << BSHIFT) | (unsigned)(c & 255);
        }
    }

    // fused weight prep (grid 98 blocks; first 64 cover W1)
    int gi = blockIdx.x * 256 + t;
    if (gi < F1 * F1) {
        int k = gi >> 7, n = gi & 127;
        W1t[n * F1 + k] = to_bf(W1[gi]);
    }
    if (gi < F1 * F2) {
        int k = gi >> 4, n = gi & 15;
        W2t[n * F1 + k] = to_bf(W2[gi]);
    }
}

// ---------- per-bucket finalize: LDS-cached edges -> seg_start/counts/dinv + csr16 ----------
__global__ __launch_bounds__(256) void k_binFinal(const unsigned* __restrict__ P,
                                                  const int* __restrict__ cursor,
                                                  ushort_t* __restrict__ csr16,
                                                  int* __restrict__ seg_start,
                                                  int* __restrict__ counts,
                                                  float* __restrict__ dinv) {
    __shared__ unsigned eb[CAP];   // 24 KB edge cache
    __shared__ int cnt[256];
    __shared__ int cur[256];
    __shared__ int wtot[4];
    int t = threadIdx.x, lane = t & 63, wid = t >> 6;
    int b = blockIdx.x;
    int lo = b << BSHIFT;
    int n_nodes = min(256, N - lo);
    int m = cursor[b];             // edges in this bucket
    cnt[t] = 0;
    __syncthreads();
    const unsigned* Pb = P + (size_t)b * CAP;
    for (int k = t; k < m; k += 256) {
        unsigned u = Pb[k];
        eb[k] = u;
        atomicAdd(&cnt[u & 255], 1);
    }
    __syncthreads();
    int v = cnt[t];
    int incl = v;
#pragma unroll
    for (int d = 1; d < 64; d <<= 1) {
        int u = __shfl_up(incl, d, 64);
        if (lane >= d) incl += u;
    }
    if (lane == 63) wtot[wid] = incl;
    __syncthreads();
    int wb = 0;
    for (int w = 0; w < wid; ++w) wb += wtot[w];
    int o = b * CAP + wb + incl - v;  // padded-global offset (csr16 mirrors P's layout)
    cur[t] = o;
    if (t < n_nodes) {
        seg_start[lo + t] = o;
        counts[lo + t] = v;
        dinv[lo + t] = rsqrtf((float)v + 1.f);
    }
    __syncthreads();
    for (int k = t; k < m; k += 256) {
        unsigned u = eb[k];
        int pos = atomicAdd(&cur[u & 255], 1);
        csr16[pos] = (ushort_t)(u >> BSHIFT);
    }
}

// ---------- GEMM1 (MFMA bf16): h1s = bf16(dinv[r] * (x @ W1)[r]) ----------
__global__ __launch_bounds__(256) void k_gemm1_mfma(const float* __restrict__ x,
                                                    const ushort_t* __restrict__ W1t,
                                                    const float* __restrict__ dinv,
                                                    ushort_t* __restrict__ h1s) {
    __shared__ ushort_t Wl[F1 * 136];
    int t = threadIdx.x;
    for (int i = t; i < F1 * 16; i += 256) {
        int n = i >> 4, c = (i & 15) * 8;
        *(int4*)&Wl[n * 136 + c] = *(const int4*)&W1t[n * F1 + c];
    }
    __syncthreads();

    int lane = t & 63, wv = t >> 6;
    int quad = lane >> 4, l15 = lane & 15;
    int arow = blockIdx.x * 64 + wv * 16 + l15;
    int rclamp = min(arow, N - 1);
    f32x4 acc[8] = {};

#pragma unroll
    for (int kk = 0; kk < 4; ++kk) {
        int k0 = kk * 32 + quad * 8;
        const float* xp = x + (size_t)rclamp * F1 + k0;
        float4 u0 = *(const float4*)xp;
        float4 u1 = *(const float4*)(xp + 4);
        bf16x8 a;
        a[0] = (__bf16)u0.x; a[1] = (__bf16)u0.y; a[2] = (__bf16)u0.z; a[3] = (__bf16)u0.w;
        a[4] = (__bf16)u1.x; a[5] = (__bf16)u1.y; a[6] = (__bf16)u1.z; a[7] = (__bf16)u1.w;
#pragma unroll
        for (int ct = 0; ct < 8; ++ct) {
            bf16x8 b = *(const bf16x8*)&Wl[(ct * 16 + l15) * 136 + k0];
            acc[ct] = __builtin_amdgcn_mfma_f32_16x16x32_bf16(a, b, acc[ct], 0, 0, 0);
        }
    }

    int orow0 = blockIdx.x * 64 + wv * 16 + quad * 4;
#pragma unroll
    for (int r = 0; r < 4; ++r) {
        int orow = orow0 + r;
        if (orow < N) {
            float d = dinv[orow];
#pragma unroll
            for (int ct = 0; ct < 8; ++ct)
                h1s[(size_t)orow * F1 + ct * 16 + l15] = to_bf(acc[ct][r] * d);
        }
    }
}

// ---------- Gather 1 (R6 winner): one wave/node, bf16x2/lane, x4 unroll ----------
__global__ __launch_bounds__(256) void k_gather1(const ushort_t* __restrict__ h1s,
                                                 const int* __restrict__ seg_start,
                                                 const int* __restrict__ counts,
                                                 const ushort_t* __restrict__ csr16,
                                                 const float* __restrict__ dinv,
                                                 const float* __restrict__ b1,
                                                 ushort_t* __restrict__ h1rb) {
    int c = (blockIdx.x * 256 + threadIdx.x) >> 6;
    int lane = threadIdx.x & 63;
    if (c >= N) return;
    int s = seg_start[c], e = s + counts[c];
    float ax = 0.f, ay = 0.f;
    int k = s;
    for (; k + 4 <= e; k += 4) {
        int r0 = csr16[k], r1 = csr16[k + 1], r2 = csr16[k + 2], r3 = csr16[k + 3];
        unsigned u0 = ((const unsigned*)(h1s + (size_t)r0 * F1))[lane];
        unsigned u1 = ((const unsigned*)(h1s + (size_t)r1 * F1))[lane];
        unsigned u2 = ((const unsigned*)(h1s + (size_t)r2 * F1))[lane];
        unsigned u3 = ((const unsigned*)(h1s + (size_t)r3 * F1))[lane];
        ax += (blo(u0) + blo(u1)) + (blo(u2) + blo(u3));
        ay += (bhi(u0) + bhi(u1)) + (bhi(u2) + bhi(u3));
    }
    for (; k < e; ++k) {
        unsigned u = ((const unsigned*)(h1s + (size_t)csr16[k] * F1))[lane];
        ax += blo(u);
        ay += bhi(u);
    }
    unsigned us = ((const unsigned*)(h1s + (size_t)c * F1))[lane];
    ax += blo(us);
    ay += bhi(us);
    float dc = dinv[c];
    float2 bb = ((const float2*)b1)[lane];
    float o0 = fmaxf(fmaf(dc, ax, bb.x), 0.f);
    float o1 = fmaxf(fmaf(dc, ay, bb.y), 0.f);
    unsigned pw = (unsigned)to_bf(o0) | ((unsigned)to_bf(o1) << 16);
    ((unsigned*)(h1rb + (size_t)c * F1))[lane] = pw;
}

// ---------- GEMM2 (MFMA bf16): h2s = bf16(dinv[r] * (h1r @ W2)[r]) ----------
__global__ __launch_bounds__(256) void k_gemm2_mfma(const ushort_t* __restrict__ h1rb,
                                                    const ushort_t* __restrict__ W2t,
                                                    const float* __restrict__ dinv,
                                                    ushort_t* __restrict__ h2s) {
    int t = threadIdx.x, lane = t & 63, wv = t >> 6;
    int quad = lane >> 4, l15 = lane & 15;
    int arow = blockIdx.x * 64 + wv * 16 + l15;
    int rclamp = min(arow, N - 1);
    f32x4 acc = {};
#pragma unroll
    for (int kk = 0; kk < 4; ++kk) {
        int k0 = kk * 32 + quad * 8;
        bf16x8 a = *(const bf16x8*)(h1rb + (size_t)rclamp * F1 + k0);
        bf16x8 b = *(const bf16x8*)(W2t + l15 * F1 + k0);
        acc = __builtin_amdgcn_mfma_f32_16x16x32_bf16(a, b, acc, 0, 0, 0);
    }
    int orow0 = blockIdx.x * 64 + wv * 16 + quad * 4;
#pragma unroll
    for (int r = 0; r < 4; ++r) {
        int orow = orow0 + r;
        if (orow < N)
            h2s[(size_t)orow * F2 + l15] = to_bf(acc[r] * dinv[orow]);
    }
}

// ---------- Gather 2 + log_softmax: 8 lanes/node ----------
__global__ __launch_bounds__(256) void k_gather2(const ushort_t* __restrict__ h2s,
                                                 const int* __restrict__ seg_start,
                                                 const int* __restrict__ counts,
                                                 const ushort_t* __restrict__ csr16,
                                                 const float* __restrict__ dinv,
                                                 const float* __restrict__ b2,
                                                 float* __restrict__ out) {
    int idx = blockIdx.x * 256 + threadIdx.x;
    int node = idx >> 3, sub = idx & 7;
    if (node >= N) return;
    int s = seg_start[node], e = s + counts[node];
    float ax = 0.f, ay = 0.f;
    int k = s;
    for (; k + 4 <= e; k += 4) {
        int r0 = csr16[k], r1 = csr16[k + 1], r2 = csr16[k + 2], r3 = csr16[k + 3];
        unsigned u0 = ((const unsigned*)(h2s + (size_t)r0 * F2))[sub];
        unsigned u1 = ((const unsigned*)(h2s + (size_t)r1 * F2))[sub];
        unsigned u2 = ((const unsigned*)(h2s + (size_t)r2 * F2))[sub];
        unsigned u3 = ((const unsigned*)(h2s + (size_t)r3 * F2))[sub];
        ax += (blo(u0) + blo(u1)) + (blo(u2) + blo(u3));
        ay += (bhi(u0) + bhi(u1)) + (bhi(u2) + bhi(u3));
    }
    for (; k < e; ++k) {
        unsigned u = ((const unsigned*)(h2s + (size_t)csr16[k] * F2))[sub];
        ax += blo(u);
        ay += bhi(u);
    }
    unsigned us = ((const unsigned*)(h2s + (size_t)node * F2))[sub];
    ax += blo(us);
    ay += bhi(us);
    float dc = dinv[node];
    float2 bb = ((const float2*)b2)[sub];
    float v0 = fmaf(dc, ax, bb.x);
    float v1 = fmaf(dc, ay, bb.y);
    float mx = fmaxf(v0, v1);
#pragma unroll
    for (int m = 1; m < 8; m <<= 1) mx = fmaxf(mx, __shfl_xor(mx, m));
    float sm = expf(v0 - mx) + expf(v1 - mx);
#pragma unroll
    for (int m = 1; m < 8; m <<= 1) sm += __shfl_xor(sm, m);
    float lse = mx + logf(sm);
    float2 o;
    o.x = v0 - lse;
    o.y = v1 - lse;
    ((float2*)(out + (size_t)node * F2))[sub] = o;
}

extern "C" void kernel_launch(void* const* d_in, const int* in_sizes, int n_in,
                              void* d_out, int out_size, void* d_ws, size_t ws_size,
                              hipStream_t stream) {
    const float* x  = (const float*)d_in[0];
    const int*   ei = (const int*)d_in[1];
    const float* W1 = (const float*)d_in[2];
    const float* b1 = (const float*)d_in[3];
    const float* W2 = (const float*)d_in[4];
    const float* b2 = (const float*)d_in[5];
    const int* row = ei;
    const int* col = ei + E;

    char* ws = (char*)d_ws;
    int*      cursor    = (int*)ws;      ws += 256 * 4;
    unsigned* P         = (unsigned*)ws; ws += (size_t)NBUCKET * CAP * 4;
    ushort_t* csr16     = (ushort_t*)ws; ws += (size_t)NBUCKET * CAP * 2;
    int*      seg_start = (int*)ws;      ws += (size_t)N * 4;
    int*      counts    = (int*)ws;      ws += (size_t)N * 4;
    float*    dinv      = (float*)ws;    ws += (size_t)N * 4;
    ushort_t* W1t       = (ushort_t*)ws; ws += (size_t)F1 * F1 * 2;
    ushort_t* W2t       = (ushort_t*)ws; ws += (size_t)F2 * F1 * 2;
    ushort_t* h1s       = (ushort_t*)ws; ws += (size_t)N * F1 * 2;
    ushort_t* h1rb      = (ushort_t*)ws; ws += (size_t)N * F1 * 2;
    ushort_t* h2s       = (ushort_t*)ws; ws += (size_t)N * F2 * 2;

    hipMemsetAsync(cursor, 0, 256 * 4, stream);

    int nbin_blocks = (E + CHUNK - 1) / CHUNK;  // 98
    k_scatterP<<<nbin_blocks, 256, 0, stream>>>(row, col, cursor, P, W1, W2, W1t, W2t);
    k_binFinal<<<NBUCKET, 256, 0, stream>>>(P, cursor, csr16, seg_start, counts, dinv);

    k_gemm1_mfma<<<(N + 63) / 64, 256, 0, stream>>>(x, W1t, dinv, h1s);
    k_gather1<<<((size_t)N * 64 + 255) / 256, 256, 0, stream>>>(h1s, seg_start, counts, csr16,
                                                                dinv, b1, h1rb);

    k_gemm2_mfma<<<(N + 63) / 64, 256, 0, stream>>>(h1rb, W2t, dinv, h2s);
    k_gather2<<<((size_t)N * 8 + 255) / 256, 256, 0, stream>>>(h2s, seg_start, counts, csr16,
                                                               dinv, b2, (float*)d_out);
}

// Round 10
// 169.773 us; speedup vs baseline: 1.4244x; 1.0866x over previous
//
#include <hip/hip_runtime.h>
#include <math.h>

constexpr int N  = 50000;
constexpr int E  = 800000;
constexpr int F1 = 128;
constexpr int F2 = 16;
constexpr int BSHIFT  = 8;                    // 256-node buckets
constexpr int NBUCKET = (N + 255) >> BSHIFT;  // 196
constexpr int CHUNK   = 2048;                 // edges per block in scatterP (391 blocks)
constexpr int CAP     = 6144;                 // per-bucket capacity (mean 4096, sigma 64)

typedef unsigned short ushort_t;
typedef __bf16 bf16x8 __attribute__((ext_vector_type(8)));
typedef float  f32x4  __attribute__((ext_vector_type(4)));

static __device__ __forceinline__ float blo(unsigned u) { return __uint_as_float(u << 16); }
static __device__ __forceinline__ float bhi(unsigned u) { return __uint_as_float(u & 0xffff0000u); }
static __device__ __forceinline__ ushort_t to_bf(float f) { __bf16 h = (__bf16)f; return *(ushort_t*)&h; }

// ---------- fused bucket scatter + weight prep ----------
// P[b*CAP + i] = row<<8 | (col & 255), per-bucket cursors in global
__global__ __launch_bounds__(256) void k_scatterP(const int* __restrict__ row,
                                                  const int* __restrict__ col,
                                                  int* __restrict__ cursor,
                                                  unsigned* __restrict__ P,
                                                  const float* __restrict__ W1,
                                                  const float* __restrict__ W2,
                                                  ushort_t* __restrict__ W1t,
                                                  ushort_t* __restrict__ W2t) {
    __shared__ int hist[NBUCKET];
    __shared__ int cur[NBUCKET];
    int t = threadIdx.x;
    if (t < NBUCKET) hist[t] = 0;
    __syncthreads();
    int base = blockIdx.x * CHUNK;
#pragma unroll
    for (int i = 0; i < CHUNK / 256; ++i) {
        int e = base + i * 256 + t;
        if (e < E) atomicAdd(&hist[col[e] >> BSHIFT], 1);
    }
    __syncthreads();
    if (t < NBUCKET) cur[t] = t * CAP + atomicAdd(&cursor[t], hist[t]);
    __syncthreads();
#pragma unroll
    for (int i = 0; i < CHUNK / 256; ++i) {
        int e = base + i * 256 + t;
        if (e < E) {
            int c = col[e];
            int pos = atomicAdd(&cur[c >> BSHIFT], 1);
            P[pos] = ((unsigned)row[e] << BSHIFT) | (unsigned)(c & 255);
        }
    }

    // fused weight prep (grid 391 blocks; first 64 cover W1)
    int gi = blockIdx.x * 256 + t;
    if (gi < F1 * F1) {
        int k = gi >> 7, n = gi & 127;
        W1t[n * F1 + k] = to_bf(W1[gi]);
    }
    if (gi < F1 * F2) {
        int k = gi >> 4, n = gi & 15;
        W2t[n * F1 + k] = to_bf(W2[gi]);
    }
}

// ---------- per-bucket finalize: LDS-cached edges -> seg_start/counts/dinv + csr16 ----------
__global__ __launch_bounds__(512) void k_binFinal(const unsigned* __restrict__ P,
                                                  const int* __restrict__ cursor,
                                                  ushort_t* __restrict__ csr16,
                                                  int* __restrict__ seg_start,
                                                  int* __restrict__ counts,
                                                  float* __restrict__ dinv) {
    __shared__ unsigned eb[CAP];   // 24 KB edge cache
    __shared__ int cnt[256];
    __shared__ int cur[256];
    __shared__ int wtot[4];
    int t = threadIdx.x;
    int b = blockIdx.x;
    int lo = b << BSHIFT;
    int n_nodes = min(256, N - lo);
    int m = cursor[b];             // edges in this bucket
    if (t < 256) cnt[t] = 0;
    __syncthreads();
    const unsigned* Pb = P + (size_t)b * CAP;
    for (int k = t; k < m; k += 512) {
        unsigned u = Pb[k];
        eb[k] = u;
        atomicAdd(&cnt[u & 255], 1);
    }
    __syncthreads();
    int lane = t & 63, wid = t >> 6;
    int v = 0, incl = 0;
    if (t < 256) {
        v = cnt[t];
        incl = v;
#pragma unroll
        for (int d = 1; d < 64; d <<= 1) {
            int u = __shfl_up(incl, d, 64);
            if (lane >= d) incl += u;
        }
        if (lane == 63) wtot[wid] = incl;
    }
    __syncthreads();
    if (t < 256) {
        int wb = 0;
        for (int w = 0; w < wid; ++w) wb += wtot[w];
        int o = b * CAP + wb + incl - v;  // padded-global offset (csr16 mirrors P's layout)
        cur[t] = o;
        if (t < n_nodes) {
            seg_start[lo + t] = o;
            counts[lo + t] = v;
            dinv[lo + t] = rsqrtf((float)v + 1.f);
        }
    }
    __syncthreads();
    for (int k = t; k < m; k += 512) {
        unsigned u = eb[k];
        int pos = atomicAdd(&cur[u & 255], 1);
        csr16[pos] = (ushort_t)(u >> BSHIFT);
    }
}

// ---------- GEMM1 (MFMA bf16): h1s = bf16(dinv[r] * (x @ W1)[r]) ----------
__global__ __launch_bounds__(256) void k_gemm1_mfma(const float* __restrict__ x,
                                                    const ushort_t* __restrict__ W1t,
                                                    const float* __restrict__ dinv,
                                                    ushort_t* __restrict__ h1s) {
    __shared__ ushort_t Wl[F1 * 136];
    int t = threadIdx.x;
    for (int i = t; i < F1 * 16; i += 256) {
        int n = i >> 4, c = (i & 15) * 8;
        *(int4*)&Wl[n * 136 + c] = *(const int4*)&W1t[n * F1 + c];
    }
    __syncthreads();

    int lane = t & 63, wv = t >> 6;
    int quad = lane >> 4, l15 = lane & 15;
    int arow = blockIdx.x * 64 + wv * 16 + l15;
    int rclamp = min(arow, N - 1);
    f32x4 acc[8] = {};

#pragma unroll
    for (int kk = 0; kk < 4; ++kk) {
        int k0 = kk * 32 + quad * 8;
        const float* xp = x + (size_t)rclamp * F1 + k0;
        float4 u0 = *(const float4*)xp;
        float4 u1 = *(const float4*)(xp + 4);
        bf16x8 a;
        a[0] = (__bf16)u0.x; a[1] = (__bf16)u0.y; a[2] = (__bf16)u0.z; a[3] = (__bf16)u0.w;
        a[4] = (__bf16)u1.x; a[5] = (__bf16)u1.y; a[6] = (__bf16)u1.z; a[7] = (__bf16)u1.w;
#pragma unroll
        for (int ct = 0; ct < 8; ++ct) {
            bf16x8 b = *(const bf16x8*)&Wl[(ct * 16 + l15) * 136 + k0];
            acc[ct] = __builtin_amdgcn_mfma_f32_16x16x32_bf16(a, b, acc[ct], 0, 0, 0);
        }
    }

    int orow0 = blockIdx.x * 64 + wv * 16 + quad * 4;
#pragma unroll
    for (int r = 0; r < 4; ++r) {
        int orow = orow0 + r;
        if (orow < N) {
            float d = dinv[orow];
#pragma unroll
            for (int ct = 0; ct < 8; ++ct)
                h1s[(size_t)orow * F1 + ct * 16 + l15] = to_bf(acc[ct][r] * d);
        }
    }
}

// ---------- Gather 1: one wave/node, bf16x2/lane, x4 unroll ----------
__global__ __launch_bounds__(256) void k_gather1(const ushort_t* __restrict__ h1s,
                                                 const int* __restrict__ seg_start,
                                                 const int* __restrict__ counts,
                                                 const ushort_t* __restrict__ csr16,
                                                 const float* __restrict__ dinv,
                                                 const float* __restrict__ b1,
                                                 ushort_t* __restrict__ h1rb) {
    int c = (blockIdx.x * 256 + threadIdx.x) >> 6;
    int lane = threadIdx.x & 63;
    if (c >= N) return;
    int s = seg_start[c], e = s + counts[c];
    float ax = 0.f, ay = 0.f;
    int k = s;
    for (; k + 4 <= e; k += 4) {
        int r0 = csr16[k], r1 = csr16[k + 1], r2 = csr16[k + 2], r3 = csr16[k + 3];
        unsigned u0 = ((const unsigned*)(h1s + (size_t)r0 * F1))[lane];
        unsigned u1 = ((const unsigned*)(h1s + (size_t)r1 * F1))[lane];
        unsigned u2 = ((const unsigned*)(h1s + (size_t)r2 * F1))[lane];
        unsigned u3 = ((const unsigned*)(h1s + (size_t)r3 * F1))[lane];
        ax += (blo(u0) + blo(u1)) + (blo(u2) + blo(u3));
        ay += (bhi(u0) + bhi(u1)) + (bhi(u2) + bhi(u3));
    }
    for (; k < e; ++k) {
        unsigned u = ((const unsigned*)(h1s + (size_t)csr16[k] * F1))[lane];
        ax += blo(u);
        ay += bhi(u);
    }
    unsigned us = ((const unsigned*)(h1s + (size_t)c * F1))[lane];
    ax += blo(us);
    ay += bhi(us);
    float dc = dinv[c];
    float2 bb = ((const float2*)b1)[lane];
    float o0 = fmaxf(fmaf(dc, ax, bb.x), 0.f);
    float o1 = fmaxf(fmaf(dc, ay, bb.y), 0.f);
    unsigned pw = (unsigned)to_bf(o0) | ((unsigned)to_bf(o1) << 16);
    ((unsigned*)(h1rb + (size_t)c * F1))[lane] = pw;
}

// ---------- GEMM2 (MFMA bf16): h2s = bf16(dinv[r] * (h1r @ W2)[r]) ----------
__global__ __launch_bounds__(256) void k_gemm2_mfma(const ushort_t* __restrict__ h1rb,
                                                    const ushort_t* __restrict__ W2t,
                                                    const float* __restrict__ dinv,
                                                    ushort_t* __restrict__ h2s) {
    int t = threadIdx.x, lane = t & 63, wv = t >> 6;
    int quad = lane >> 4, l15 = lane & 15;
    int arow = blockIdx.x * 64 + wv * 16 + l15;
    int rclamp = min(arow, N - 1);
    f32x4 acc = {};
#pragma unroll
    for (int kk = 0; kk < 4; ++kk) {
        int k0 = kk * 32 + quad * 8;
        bf16x8 a = *(const bf16x8*)(h1rb + (size_t)rclamp * F1 + k0);
        bf16x8 b = *(const bf16x8*)(W2t + l15 * F1 + k0);
        acc = __builtin_amdgcn_mfma_f32_16x16x32_bf16(a, b, acc, 0, 0, 0);
    }
    int orow0 = blockIdx.x * 64 + wv * 16 + quad * 4;
#pragma unroll
    for (int r = 0; r < 4; ++r) {
        int orow = orow0 + r;
        if (orow < N)
            h2s[(size_t)orow * F2 + l15] = to_bf(acc[r] * dinv[orow]);
    }
}

// ---------- Gather 2 + log_softmax: 8 lanes/node ----------
__global__ __launch_bounds__(256) void k_gather2(const ushort_t* __restrict__ h2s,
                                                 const int* __restrict__ seg_start,
                                                 const int* __restrict__ counts,
                                                 const ushort_t* __restrict__ csr16,
                                                 const float* __restrict__ dinv,
                                                 const float* __restrict__ b2,
                                                 float* __restrict__ out) {
    int idx = blockIdx.x * 256 + threadIdx.x;
    int node = idx >> 3, sub = idx & 7;
    if (node >= N) return;
    int s = seg_start[node], e = s + counts[node];
    float ax = 0.f, ay = 0.f;
    int k = s;
    for (; k + 4 <= e; k += 4) {
        int r0 = csr16[k], r1 = csr16[k + 1], r2 = csr16[k + 2], r3 = csr16[k + 3];
        unsigned u0 = ((const unsigned*)(h2s + (size_t)r0 * F2))[sub];
        unsigned u1 = ((const unsigned*)(h2s + (size_t)r1 * F2))[sub];
        unsigned u2 = ((const unsigned*)(h2s + (size_t)r2 * F2))[sub];
        unsigned u3 = ((const unsigned*)(h2s + (size_t)r3 * F2))[sub];
        ax += (blo(u0) + blo(u1)) + (blo(u2) + blo(u3));
        ay += (bhi(u0) + bhi(u1)) + (bhi(u2) + bhi(u3));
    }
    for (; k < e; ++k) {
        unsigned u = ((const unsigned*)(h2s + (size_t)csr16[k] * F2))[sub];
        ax += blo(u);
        ay += bhi(u);
    }
    unsigned us = ((const unsigned*)(h2s + (size_t)node * F2))[sub];
    ax += blo(us);
    ay += bhi(us);
    float dc = dinv[node];
    float2 bb = ((const float2*)b2)[sub];
    float v0 = fmaf(dc, ax, bb.x);
    float v1 = fmaf(dc, ay, bb.y);
    float mx = fmaxf(v0, v1);
#pragma unroll
    for (int m = 1; m < 8; m <<= 1) mx = fmaxf(mx, __shfl_xor(mx, m));
    float sm = expf(v0 - mx) + expf(v1 - mx);
#pragma unroll
    for (int m = 1; m < 8; m <<= 1) sm += __shfl_xor(sm, m);
    float lse = mx + logf(sm);
    float2 o;
    o.x = v0 - lse;
    o.y = v1 - lse;
    ((float2*)(out + (size_t)node * F2))[sub] = o;
}

extern "C" void kernel_launch(void* const* d_in, const int* in_sizes, int n_in,
                              void* d_out, int out_size, void* d_ws, size_t ws_size,
                              hipStream_t stream) {
    const float* x  = (const float*)d_in[0];
    const int*   ei = (const int*)d_in[1];
    const float* W1 = (const float*)d_in[2];
    const float* b1 = (const float*)d_in[3];
    const float* W2 = (const float*)d_in[4];
    const float* b2 = (const float*)d_in[5];
    const int* row = ei;
    const int* col = ei + E;

    char* ws = (char*)d_ws;
    int*      cursor    = (int*)ws;      ws += 256 * 4;
    unsigned* P         = (unsigned*)ws; ws += (size_t)NBUCKET * CAP * 4;
    ushort_t* csr16     = (ushort_t*)ws; ws += (size_t)NBUCKET * CAP * 2;
    int*      seg_start = (int*)ws;      ws += (size_t)N * 4;
    int*      counts    = (int*)ws;      ws += (size_t)N * 4;
    float*    dinv      = (float*)ws;    ws += (size_t)N * 4;
    ushort_t* W1t       = (ushort_t*)ws; ws += (size_t)F1 * F1 * 2;
    ushort_t* W2t       = (ushort_t*)ws; ws += (size_t)F2 * F1 * 2;
    ushort_t* h1s       = (ushort_t*)ws; ws += (size_t)N * F1 * 2;
    ushort_t* h1rb      = (ushort_t*)ws; ws += (size_t)N * F1 * 2;
    ushort_t* h2s       = (ushort_t*)ws; ws += (size_t)N * F2 * 2;

    hipMemsetAsync(cursor, 0, 256 * 4, stream);

    int nbin_blocks = (E + CHUNK - 1) / CHUNK;  // 391
    k_scatterP<<<nbin_blocks, 256, 0, stream>>>(row, col, cursor, P, W1, W2, W1t, W2t);
    k_binFinal<<<NBUCKET, 512, 0, stream>>>(P, cursor, csr16, seg_start, counts, dinv);

    k_gemm1_mfma<<<(N + 63) / 64, 256, 0, stream>>>(x, W1t, dinv, h1s);
    k_gather1<<<((size_t)N * 64 + 255) / 256, 256, 0, stream>>>(h1s, seg_start, counts, csr16,
                                                                dinv, b1, h1rb);

    k_gemm2_mfma<<<(N + 63) / 64, 256, 0, stream>>>(h1rb, W2t, dinv, h2s);
    k_gather2<<<((size_t)N * 8 + 255) / 256, 256, 0, stream>>>(h2s, seg_start, counts, csr16,
                                                               dinv, b2, (float*)d_out);
}

// Round 11
// 164.419 us; speedup vs baseline: 1.4708x; 1.0326x over previous
//
#include <hip/hip_runtime.h>
#include <math.h>

constexpr int N  = 50000;
constexpr int E  = 800000;
constexpr int F1 = 128;
constexpr int F2 = 16;
constexpr int BSHIFT  = 8;                    // 256-node buckets
constexpr int NBUCKET = (N + 255) >> BSHIFT;  // 196
constexpr int CHUNK   = 2048;                 // edges per block in scatterP (391 blocks)
constexpr int CAP     = 6144;                 // per-bucket capacity (mean 4096, sigma 64)

typedef unsigned short ushort_t;
typedef unsigned char  uchar_t;
typedef __bf16 bf16x8 __attribute__((ext_vector_type(8)));
typedef float  f32x4  __attribute__((ext_vector_type(4)));

static __device__ __forceinline__ float blo(unsigned u) { return __uint_as_float(u << 16); }
static __device__ __forceinline__ float bhi(unsigned u) { return __uint_as_float(u & 0xffff0000u); }
static __device__ __forceinline__ ushort_t to_bf(float f) { __bf16 h = (__bf16)f; return *(ushort_t*)&h; }
static __device__ __forceinline__ uchar_t to_fp8(float f) {
    return (uchar_t)(__builtin_amdgcn_cvt_pk_fp8_f32(f, f, 0, false) & 0xff);
}

// ---------- fused bucket scatter + weight prep ----------
// P[b*CAP + i] = row<<8 | (col & 255), per-bucket cursors in global
__global__ __launch_bounds__(256) void k_scatterP(const int* __restrict__ row,
                                                  const int* __restrict__ col,
                                                  int* __restrict__ cursor,
                                                  unsigned* __restrict__ P,
                                                  const float* __restrict__ W1,
                                                  const float* __restrict__ W2,
                                                  ushort_t* __restrict__ W1t,
                                                  ushort_t* __restrict__ W2t) {
    __shared__ int hist[NBUCKET];
    __shared__ int cur[NBUCKET];
    int t = threadIdx.x;
    if (t < NBUCKET) hist[t] = 0;
    __syncthreads();
    int base = blockIdx.x * CHUNK;
#pragma unroll
    for (int i = 0; i < CHUNK / 256; ++i) {
        int e = base + i * 256 + t;
        if (e < E) atomicAdd(&hist[col[e] >> BSHIFT], 1);
    }
    __syncthreads();
    if (t < NBUCKET) cur[t] = t * CAP + atomicAdd(&cursor[t], hist[t]);
    __syncthreads();
#pragma unroll
    for (int i = 0; i < CHUNK / 256; ++i) {
        int e = base + i * 256 + t;
        if (e < E) {
            int c = col[e];
            int pos = atomicAdd(&cur[c >> BSHIFT], 1);
            P[pos] = ((unsigned)row[e] << BSHIFT) | (unsigned)(c & 255);
        }
    }

    // fused weight prep (grid 391 blocks; first 64 cover W1)
    int gi = blockIdx.x * 256 + t;
    if (gi < F1 * F1) {
        int k = gi >> 7, n = gi & 127;
        W1t[n * F1 + k] = to_bf(W1[gi]);
    }
    if (gi < F1 * F2) {
        int k = gi >> 4, n = gi & 15;
        W2t[n * F1 + k] = to_bf(W2[gi]);
    }
}

// ---------- per-bucket finalize: LDS-cached edges -> seg_start/counts/dinv + csr16 ----------
__global__ __launch_bounds__(512) void k_binFinal(const unsigned* __restrict__ P,
                                                  const int* __restrict__ cursor,
                                                  ushort_t* __restrict__ csr16,
                                                  int* __restrict__ seg_start,
                                                  int* __restrict__ counts,
                                                  float* __restrict__ dinv) {
    __shared__ unsigned eb[CAP];   // 24 KB edge cache
    __shared__ int cnt[256];
    __shared__ int cur[256];
    __shared__ int wtot[4];
    int t = threadIdx.x;
    int b = blockIdx.x;
    int lo = b << BSHIFT;
    int n_nodes = min(256, N - lo);
    int m = cursor[b];             // edges in this bucket
    if (t < 256) cnt[t] = 0;
    __syncthreads();
    const unsigned* Pb = P + (size_t)b * CAP;
    for (int k = t; k < m; k += 512) {
        unsigned u = Pb[k];
        eb[k] = u;
        atomicAdd(&cnt[u & 255], 1);
    }
    __syncthreads();
    int lane = t & 63, wid = t >> 6;
    int v = 0, incl = 0;
    if (t < 256) {
        v = cnt[t];
        incl = v;
#pragma unroll
        for (int d = 1; d < 64; d <<= 1) {
            int u = __shfl_up(incl, d, 64);
            if (lane >= d) incl += u;
        }
        if (lane == 63) wtot[wid] = incl;
    }
    __syncthreads();
    if (t < 256) {
        int wb = 0;
        for (int w = 0; w < wid; ++w) wb += wtot[w];
        int o = b * CAP + wb + incl - v;  // padded-global offset (csr16 mirrors P's layout)
        cur[t] = o;
        if (t < n_nodes) {
            seg_start[lo + t] = o;
            counts[lo + t] = v;
            dinv[lo + t] = rsqrtf((float)v + 1.f);
        }
    }
    __syncthreads();
    for (int k = t; k < m; k += 512) {
        unsigned u = eb[k];
        int pos = atomicAdd(&cur[u & 255], 1);
        csr16[pos] = (ushort_t)(u >> BSHIFT);
    }
}

// ---------- GEMM1 (MFMA bf16): h1q = fp8(dinv[r] * (x @ W1)[r]) ----------
__global__ __launch_bounds__(256) void k_gemm1_mfma(const float* __restrict__ x,
                                                    const ushort_t* __restrict__ W1t,
                                                    const float* __restrict__ dinv,
                                                    uchar_t* __restrict__ h1q) {
    __shared__ ushort_t Wl[F1 * 136];
    int t = threadIdx.x;
    for (int i = t; i < F1 * 16; i += 256) {
        int n = i >> 4, c = (i & 15) * 8;
        *(int4*)&Wl[n * 136 + c] = *(const int4*)&W1t[n * F1 + c];
    }
    __syncthreads();

    int lane = t & 63, wv = t >> 6;
    int quad = lane >> 4, l15 = lane & 15;
    int arow = blockIdx.x * 64 + wv * 16 + l15;
    int rclamp = min(arow, N - 1);
    f32x4 acc[8] = {};

#pragma unroll
    for (int kk = 0; kk < 4; ++kk) {
        int k0 = kk * 32 + quad * 8;
        const float* xp = x + (size_t)rclamp * F1 + k0;
        float4 u0 = *(const float4*)xp;
        float4 u1 = *(const float4*)(xp + 4);
        bf16x8 a;
        a[0] = (__bf16)u0.x; a[1] = (__bf16)u0.y; a[2] = (__bf16)u0.z; a[3] = (__bf16)u0.w;
        a[4] = (__bf16)u1.x; a[5] = (__bf16)u1.y; a[6] = (__bf16)u1.z; a[7] = (__bf16)u1.w;
#pragma unroll
        for (int ct = 0; ct < 8; ++ct) {
            bf16x8 b = *(const bf16x8*)&Wl[(ct * 16 + l15) * 136 + k0];
            acc[ct] = __builtin_amdgcn_mfma_f32_16x16x32_bf16(a, b, acc[ct], 0, 0, 0);
        }
    }

    int orow0 = blockIdx.x * 64 + wv * 16 + quad * 4;
#pragma unroll
    for (int r = 0; r < 4; ++r) {
        int orow = orow0 + r;
        if (orow < N) {
            float d = dinv[orow];
#pragma unroll
            for (int ct = 0; ct < 8; ++ct)
                h1q[(size_t)orow * F1 + ct * 16 + l15] = to_fp8(acc[ct][r] * d);
        }
    }
}

// ---------- Gather 1: one wave/node, fp8x2/lane (2 B), x4 unroll ----------
// h1r = relu(dinv_c * (sum fp8dec(h1q[r]) + fp8dec(h1q[c])) + b1), bf16 out
__global__ __launch_bounds__(256) void k_gather1(const uchar_t* __restrict__ h1q,
                                                 const int* __restrict__ seg_start,
                                                 const int* __restrict__ counts,
                                                 const ushort_t* __restrict__ csr16,
                                                 const float* __restrict__ dinv,
                                                 const float* __restrict__ b1,
                                                 ushort_t* __restrict__ h1rb) {
    int c = (blockIdx.x * 256 + threadIdx.x) >> 6;
    int lane = threadIdx.x & 63;
    if (c >= N) return;
    int s = seg_start[c], e = s + counts[c];
    float ax = 0.f, ay = 0.f;
    int k = s;
    for (; k + 4 <= e; k += 4) {
        int r0 = csr16[k], r1 = csr16[k + 1], r2 = csr16[k + 2], r3 = csr16[k + 3];
        unsigned u0 = ((const ushort_t*)(h1q + (size_t)r0 * F1))[lane];
        unsigned u1 = ((const ushort_t*)(h1q + (size_t)r1 * F1))[lane];
        unsigned u2 = ((const ushort_t*)(h1q + (size_t)r2 * F1))[lane];
        unsigned u3 = ((const ushort_t*)(h1q + (size_t)r3 * F1))[lane];
        ax += (__builtin_amdgcn_cvt_f32_fp8(u0, 0) + __builtin_amdgcn_cvt_f32_fp8(u1, 0)) +
              (__builtin_amdgcn_cvt_f32_fp8(u2, 0) + __builtin_amdgcn_cvt_f32_fp8(u3, 0));
        ay += (__builtin_amdgcn_cvt_f32_fp8(u0, 1) + __builtin_amdgcn_cvt_f32_fp8(u1, 1)) +
              (__builtin_amdgcn_cvt_f32_fp8(u2, 1) + __builtin_amdgcn_cvt_f32_fp8(u3, 1));
    }
    for (; k < e; ++k) {
        unsigned u = ((const ushort_t*)(h1q + (size_t)csr16[k] * F1))[lane];
        ax += __builtin_amdgcn_cvt_f32_fp8(u, 0);
        ay += __builtin_amdgcn_cvt_f32_fp8(u, 1);
    }
    unsigned us = ((const ushort_t*)(h1q + (size_t)c * F1))[lane];
    ax += __builtin_amdgcn_cvt_f32_fp8(us, 0);
    ay += __builtin_amdgcn_cvt_f32_fp8(us, 1);
    float dc = dinv[c];
    float2 bb = ((const float2*)b1)[lane];
    float o0 = fmaxf(fmaf(dc, ax, bb.x), 0.f);
    float o1 = fmaxf(fmaf(dc, ay, bb.y), 0.f);
    unsigned pw = (unsigned)to_bf(o0) | ((unsigned)to_bf(o1) << 16);
    ((unsigned*)(h1rb + (size_t)c * F1))[lane] = pw;
}

// ---------- GEMM2 (MFMA bf16): h2s = bf16(dinv[r] * (h1r @ W2)[r]) ----------
__global__ __launch_bounds__(256) void k_gemm2_mfma(const ushort_t* __restrict__ h1rb,
                                                    const ushort_t* __restrict__ W2t,
                                                    const float* __restrict__ dinv,
                                                    ushort_t* __restrict__ h2s) {
    int t = threadIdx.x, lane = t & 63, wv = t >> 6;
    int quad = lane >> 4, l15 = lane & 15;
    int arow = blockIdx.x * 64 + wv * 16 + l15;
    int rclamp = min(arow, N - 1);
    f32x4 acc = {};
#pragma unroll
    for (int kk = 0; kk < 4; ++kk) {
        int k0 = kk * 32 + quad * 8;
        bf16x8 a = *(const bf16x8*)(h1rb + (size_t)rclamp * F1 + k0);
        bf16x8 b = *(const bf16x8*)(W2t + l15 * F1 + k0);
        acc = __builtin_amdgcn_mfma_f32_16x16x32_bf16(a, b, acc, 0, 0, 0);
    }
    int orow0 = blockIdx.x * 64 + wv * 16 + quad * 4;
#pragma unroll
    for (int r = 0; r < 4; ++r) {
        int orow = orow0 + r;
        if (orow < N)
            h2s[(size_t)orow * F2 + l15] = to_bf(acc[r] * dinv[orow]);
    }
}

// ---------- Gather 2 + log_softmax: 8 lanes/node ----------
__global__ __launch_bounds__(256) void k_gather2(const ushort_t* __restrict__ h2s,
                                                 const int* __restrict__ seg_start,
                                                 const int* __restrict__ counts,
                                                 const ushort_t* __restrict__ csr16,
                                                 const float* __restrict__ dinv,
                                                 const float* __restrict__ b2,
                                                 float* __restrict__ out) {
    int idx = blockIdx.x * 256 + threadIdx.x;
    int node = idx >> 3, sub = idx & 7;
    if (node >= N) return;
    int s = seg_start[node], e = s + counts[node];
    float ax = 0.f, ay = 0.f;
    int k = s;
    for (; k + 4 <= e; k += 4) {
        int r0 = csr16[k], r1 = csr16[k + 1], r2 = csr16[k + 2], r3 = csr16[k + 3];
        unsigned u0 = ((const unsigned*)(h2s + (size_t)r0 * F2))[sub];
        unsigned u1 = ((const unsigned*)(h2s + (size_t)r1 * F2))[sub];
        unsigned u2 = ((const unsigned*)(h2s + (size_t)r2 * F2))[sub];
        unsigned u3 = ((const unsigned*)(h2s + (size_t)r3 * F2))[sub];
        ax += (blo(u0) + blo(u1)) + (blo(u2) + blo(u3));
        ay += (bhi(u0) + bhi(u1)) + (bhi(u2) + bhi(u3));
    }
    for (; k < e; ++k) {
        unsigned u = ((const unsigned*)(h2s + (size_t)csr16[k] * F2))[sub];
        ax += blo(u);
        ay += bhi(u);
    }
    unsigned us = ((const unsigned*)(h2s + (size_t)node * F2))[sub];
    ax += blo(us);
    ay += bhi(us);
    float dc = dinv[node];
    float2 bb = ((const float2*)b2)[sub];
    float v0 = fmaf(dc, ax, bb.x);
    float v1 = fmaf(dc, ay, bb.y);
    float mx = fmaxf(v0, v1);
#pragma unroll
    for (int m = 1; m < 8; m <<= 1) mx = fmaxf(mx, __shfl_xor(mx, m));
    float sm = expf(v0 - mx) + expf(v1 - mx);
#pragma unroll
    for (int m = 1; m < 8; m <<= 1) sm += __shfl_xor(sm, m);
    float lse = mx + logf(sm);
    float2 o;
    o.x = v0 - lse;
    o.y = v1 - lse;
    ((float2*)(out + (size_t)node * F2))[sub] = o;
}

extern "C" void kernel_launch(void* const* d_in, const int* in_sizes, int n_in,
                              void* d_out, int out_size, void* d_ws, size_t ws_size,
                              hipStream_t stream) {
    const float* x  = (const float*)d_in[0];
    const int*   ei = (const int*)d_in[1];
    const float* W1 = (const float*)d_in[2];
    const float* b1 = (const float*)d_in[3];
    const float* W2 = (const float*)d_in[4];
    const float* b2 = (const float*)d_in[5];
    const int* row = ei;
    const int* col = ei + E;

    char* ws = (char*)d_ws;
    int*      cursor    = (int*)ws;      ws += 256 * 4;
    unsigned* P         = (unsigned*)ws; ws += (size_t)NBUCKET * CAP * 4;
    ushort_t* csr16     = (ushort_t*)ws; ws += (size_t)NBUCKET * CAP * 2;
    int*      seg_start = (int*)ws;      ws += (size_t)N * 4;
    int*      counts    = (int*)ws;      ws += (size_t)N * 4;
    float*    dinv      = (float*)ws;    ws += (size_t)N * 4;
    ushort_t* W1t       = (ushort_t*)ws; ws += (size_t)F1 * F1 * 2;
    ushort_t* W2t       = (ushort_t*)ws; ws += (size_t)F2 * F1 * 2;
    uchar_t*  h1q       = (uchar_t*)ws;  ws += (size_t)N * F1;       // fp8 e4m3
    ushort_t* h1rb      = (ushort_t*)ws; ws += (size_t)N * F1 * 2;
    ushort_t* h2s       = (ushort_t*)ws; ws += (size_t)N * F2 * 2;

    hipMemsetAsync(cursor, 0, 256 * 4, stream);

    int nbin_blocks = (E + CHUNK - 1) / CHUNK;  // 391
    k_scatterP<<<nbin_blocks, 256, 0, stream>>>(row, col, cursor, P, W1, W2, W1t, W2t);
    k_binFinal<<<NBUCKET, 512, 0, stream>>>(P, cursor, csr16, seg_start, counts, dinv);

    k_gemm1_mfma<<<(N + 63) / 64, 256, 0, stream>>>(x, W1t, dinv, h1q);
    k_gather1<<<((size_t)N * 64 + 255) / 256, 256, 0, stream>>>(h1q, seg_start, counts, csr16,
                                                                dinv, b1, h1rb);

    k_gemm2_mfma<<<(N + 63) / 64, 256, 0, stream>>>(h1rb, W2t, dinv, h2s);
    k_gather2<<<((size_t)N * 8 + 255) / 256, 256, 0, stream>>>(h2s, seg_start, counts, csr16,
                                                               dinv, b2, (float*)d_out);
}